// Round 13
// baseline (377.667 us; speedup 1.0000x reference)
//
#include <hip/hip_runtime.h>
#include <hip/hip_bf16.h>

// ---------------------------------------------------------------------------
// 3-layer GAT (eval mode) on MI355X.
//   L1: alpha1 fused into x-cast ; Xagg = softmax-gather of X (128ch, inline
//       cooperative edge weights) ; f1 = ELU(Xagg @ W1 + b1) (per-head GEMM)
//   L2: h2 = f1@W2 (epilogue computes alpha2) ; half-row-sliced gather of h2
//       (z = column half, temporally separated for L2 locality; +b2, ELU)
//   L3: h3 = f2@W3 (epilogue computes alpha3 = h3·a3) ; gather 64ch (+b3)
// ---------------------------------------------------------------------------

typedef __attribute__((ext_vector_type(8))) short bf16x8;
typedef __attribute__((ext_vector_type(4))) float f32x4;

__device__ __forceinline__ float bflo(unsigned w) { return __uint_as_float(w << 16); }
__device__ __forceinline__ float bfhi(unsigned w) { return __uint_as_float(w & 0xffff0000u); }
__device__ __forceinline__ float leaky(float x) { return x > 0.f ? x : 0.2f * x; }
__device__ __forceinline__ unsigned pack2(float a, float b) {
    unsigned ua = __bfloat16_as_ushort(__float2bfloat16(a));
    unsigned ub = __bfloat16_as_ushort(__float2bfloat16(b));
    return ua | (ub << 16);
}

// ------------------------- CSR build ---------------------------------------

__global__ void k_count(const int* __restrict__ ei, int E, int N, int* __restrict__ cnt) {
    int e = blockIdx.x * blockDim.x + threadIdx.x;
    int tot = E + N;
    if (e >= tot) return;
    int d = (e < E) ? ei[E + e] : (e - E);
    atomicAdd(&cnt[d], 1);
}

// scan of padded counts cp = (cnt+3)&~3
__global__ void k_scan1(const int* __restrict__ cnt, int N, int* __restrict__ rp,
                        int* __restrict__ blksum) {
    __shared__ int sdata[256];
    int t = threadIdx.x;
    int base = blockIdx.x * 1024;
    int v[4];
    int loc = 0;
#pragma unroll
    for (int i = 0; i < 4; i++) {
        int idx = base + t * 4 + i;
        v[i] = (idx < N) ? ((cnt[idx] + 3) & ~3) : 0;
        loc += v[i];
    }
    int x = loc;
    sdata[t] = x;
    __syncthreads();
    for (int off = 1; off < 256; off <<= 1) {
        int y = (t >= off) ? sdata[t - off] : 0;
        __syncthreads();
        x += y;
        sdata[t] = x;
        __syncthreads();
    }
    int run = x - loc;
#pragma unroll
    for (int i = 0; i < 4; i++) {
        int idx = base + t * 4 + i;
        if (idx < N) rp[idx] = run;
        run += v[i];
    }
    if (t == 255) blksum[blockIdx.x] = x;
}

// finalize rp (adds block prefix computed in-wave from blksum), init cur,
// fill pad cols. nblk <= 64.
__global__ void k_scan3(int* __restrict__ rp, const int* __restrict__ blksum,
                        const int* __restrict__ cnt, int N, int nblk,
                        int* __restrict__ cur, int* __restrict__ col) {
    __shared__ int lblk[64];
    if (threadIdx.x < 64) {
        int l = threadIdx.x;
        int v = (l < nblk) ? blksum[l] : 0;
        int x = v;
#pragma unroll
        for (int off = 1; off < 64; off <<= 1) {
            int y = __shfl_up(x, off);
            if (l >= off) x += y;
        }
        lblk[l] = x - v;  // exclusive prefix
    }
    __syncthreads();
    int i = blockIdx.x * blockDim.x + threadIdx.x;
    if (i < N) {
        int v = rp[i] + lblk[i >> 10];
        rp[i] = v;
        cur[i] = v;
        int c = cnt[i];
        int pad = ((c + 3) & ~3) - c;
        for (int p = 0; p < pad; p++) col[v + c + p] = 0;
    }
    if (i == 0) rp[N] = lblk[nblk - 1] + blksum[nblk - 1];
}

__global__ void k_fill(const int* __restrict__ ei, int E, int N, int* __restrict__ cur,
                       int* __restrict__ col) {
    int e = blockIdx.x * blockDim.x + threadIdx.x;
    int tot = E + N;
    if (e >= tot) return;
    int s, d;
    if (e < E) { s = ei[e]; d = ei[E + e]; }
    else       { s = e - E; d = e - E; }
    int p = atomicAdd(&cur[d], 1);
    col[p] = s;
}

// ------------------------- casts & small precomputes ------------------------

// One wave per row: cast x row (128 f32) -> xb (bf16), and compute
// alpha1_s/d[row,h] = x[row,:]·va8[:,h] from the f32 values. Pad rows zeroed.
__global__ void k_cast_alpha(const float* __restrict__ X, __hip_bfloat16* __restrict__ Xb,
                             const float* __restrict__ va8, float* __restrict__ as_out,
                             float* __restrict__ ad_out, int N, int Mp) {
    int w = (blockIdx.x * blockDim.x + threadIdx.x) >> 6;
    int lane = threadIdx.x & 63;
    if (w >= Mp) return;
    unsigned* xb32 = (unsigned*)Xb;
    if (w >= N) {
        xb32[(size_t)w * 64 + lane] = 0u;
        return;
    }
    float2 xv = *(const float2*)&X[(size_t)w * 128 + lane * 2];
    xb32[(size_t)w * 64 + lane] = pack2(xv.x, xv.y);
    int c0 = lane * 2;
    float4 vs0 = *(const float4*)&va8[c0 * 8];
    float4 vd0 = *(const float4*)&va8[c0 * 8 + 4];
    float4 vs1 = *(const float4*)&va8[(c0 + 1) * 8];
    float4 vd1 = *(const float4*)&va8[(c0 + 1) * 8 + 4];
    float s[8];
    s[0] = xv.x * vs0.x + xv.y * vs1.x;
    s[1] = xv.x * vs0.y + xv.y * vs1.y;
    s[2] = xv.x * vs0.z + xv.y * vs1.z;
    s[3] = xv.x * vs0.w + xv.y * vs1.w;
    s[4] = xv.x * vd0.x + xv.y * vd1.x;
    s[5] = xv.x * vd0.y + xv.y * vd1.y;
    s[6] = xv.x * vd0.z + xv.y * vd1.z;
    s[7] = xv.x * vd0.w + xv.y * vd1.w;
#pragma unroll
    for (int off = 32; off >= 1; off >>= 1)
#pragma unroll
        for (int j = 0; j < 8; j++) s[j] += __shfl_xor(s[j], off);
    if (lane == 0) {
        *(float4*)&as_out[w * 4] = make_float4(s[0], s[1], s[2], s[3]);
        *(float4*)&ad_out[w * 4] = make_float4(s[4], s[5], s[6], s[7]);
    }
}

__global__ void k_castT(const float* __restrict__ W, __hip_bfloat16* __restrict__ Wt,
                        int K, int Nw) {
    __shared__ float t[32][33];
    int k0 = blockIdx.x * 32, n0 = blockIdx.y * 32;
    int tx = threadIdx.x & 31, ty = threadIdx.x >> 5;
    for (int i = ty; i < 32; i += 8) t[i][tx] = W[(size_t)(k0 + i) * Nw + n0 + tx];
    __syncthreads();
    for (int i = ty; i < 32; i += 8)
        Wt[(size_t)(n0 + i) * K + k0 + tx] = __float2bfloat16(t[tx][i]);
}

// va8[c][0..3] = (W1[c, h*128:]·a_src[h]),  va8[c][4..7] = same with a_dst.
__global__ void k_va1(const float* __restrict__ W1, const float* __restrict__ asrc,
                      const float* __restrict__ adst, float* __restrict__ va8) {
    int t = threadIdx.x;        // 512 threads: c = t>>2, h = t&3
    int c = t >> 2, h = t & 3;
    const float* wrow = W1 + (size_t)c * 512 + h * 128;
    const float* av = asrc + h * 128;
    const float* dv = adst + h * 128;
    float vs = 0.f, vd = 0.f;
    for (int k = 0; k < 128; k++) {
        float wv = wrow[k];
        vs += wv * av[k];
        vd += wv * dv[k];
    }
    va8[c * 8 + h] = vs;
    va8[c * 8 + 4 + h] = vd;
}

// ------------------------- bf16 MFMA GEMM ----------------------------------
// C[row, cbase+col] = A[row, :K] @ Bt[col, :K]^T ; optional fused bias+ELU.
// ALPHA_H = 0: none.  ALPHA_H = 4: (BN=128, blockIdx.x==head) epilogue emits
// alpha[row*4+head] = C_block[row,:]·aTab[head].  ALPHA_H = 1: (BN=64) emits
// alpha[row] = C_block[row,:]·aTab.  Reduce: fr-lane shfl + LDS cross-wave.

template <int BM, int BN, bool FUSE, int ALPHA_H>
__global__ void __launch_bounds__(256) k_gemm_mfma(const __hip_bfloat16* __restrict__ A,
                                                   const __hip_bfloat16* __restrict__ Bt,
                                                   __hip_bfloat16* __restrict__ C,
                                                   int lda, int ldc, int K,
                                                   int hsA, int hsB, int hsC,
                                                   const float* __restrict__ bias,
                                                   const float* __restrict__ aSrcTab,
                                                   const float* __restrict__ aDstTab,
                                                   float* __restrict__ asOut,
                                                   float* __restrict__ adOut) {
    constexpr int BK = 64;
    constexpr int WM = BM / 2;
    constexpr int WN = BN / 2;
    constexpr int MREP = WM / 16;
    constexpr int NREP = WN / 16;

    __shared__ __hip_bfloat16 lds[(BM + BN) * BK];
    __hip_bfloat16* As = lds;
    __hip_bfloat16* Bs = lds + BM * BK;

    const int z = blockIdx.z;
    A += (size_t)z * hsA;
    Bt += (size_t)z * hsB;
    const int cbase = z * hsC;

    const int tid = threadIdx.x;
    const int wave = tid >> 6;
    const int lane = tid & 63;
    const int wm0 = (wave >> 1) * WM;
    const int wn0 = (wave & 1) * WN;
    const int m0 = blockIdx.y * BM;
    const int n0 = blockIdx.x * BN;
    const int fr = lane & 15;
    const int fq = lane >> 4;

    f32x4 acc[MREP][NREP] = {};

    for (int kt = 0; kt < K; kt += BK) {
        const __hip_bfloat16* srcA = A + (size_t)m0 * lda + kt;
#pragma unroll
        for (int it = 0; it < BM * 8 / 256; ++it) {
            int gb = it * 256 + wave * 64;
            int g = gb + lane;
            int row = g >> 3;
            int kg = (g & 7) ^ (row & 7);
            const __hip_bfloat16* gsrc = srcA + (size_t)row * lda + kg * 8;
            __builtin_amdgcn_global_load_lds(
                (const __attribute__((address_space(1))) void*)gsrc,
                (__attribute__((address_space(3))) void*)(As + gb * 8), 16, 0, 0);
        }
        const __hip_bfloat16* srcB = Bt + (size_t)n0 * K + kt;
#pragma unroll
        for (int it = 0; it < BN * 8 / 256; ++it) {
            int gb = it * 256 + wave * 64;
            int g = gb + lane;
            int row = g >> 3;
            int kg = (g & 7) ^ (row & 7);
            const __hip_bfloat16* gsrc = srcB + (size_t)row * K + kg * 8;
            __builtin_amdgcn_global_load_lds(
                (const __attribute__((address_space(1))) void*)gsrc,
                (__attribute__((address_space(3))) void*)(Bs + gb * 8), 16, 0, 0);
        }
        __syncthreads();

#pragma unroll
        for (int sl = 0; sl < 2; ++sl) {
            int ke = sl * 32 + fq * 8;
            bf16x8 af[MREP], bfr[NREP];
#pragma unroll
            for (int i = 0; i < MREP; ++i) {
                int row = wm0 + i * 16 + fr;
                int e = (row * BK + ke) ^ ((row & 7) << 3);
                af[i] = *(const bf16x8*)(As + e);
            }
#pragma unroll
            for (int j = 0; j < NREP; ++j) {
                int row = wn0 + j * 16 + fr;
                int e = (row * BK + ke) ^ ((row & 7) << 3);
                bfr[j] = *(const bf16x8*)(Bs + e);
            }
#pragma unroll
            for (int i = 0; i < MREP; ++i)
#pragma unroll
                for (int j = 0; j < NREP; ++j)
                    acc[i][j] = __builtin_amdgcn_mfma_f32_16x16x32_bf16(
                        af[i], bfr[j], acc[i][j], 0, 0, 0);
        }
        __syncthreads();
    }

#pragma unroll
    for (int i = 0; i < MREP; ++i) {
#pragma unroll
        for (int j = 0; j < NREP; ++j) {
            int colg = cbase + n0 + wn0 + j * 16 + fr;
#pragma unroll
            for (int r = 0; r < 4; ++r) {
                int rowg = m0 + wm0 + i * 16 + fq * 4 + r;
                float v = acc[i][j][r];
                if (FUSE) {
                    v += bias[colg];
                    v = v > 0.f ? v : expm1f(v);
                }
                C[(size_t)rowg * ldc + colg] = __float2bfloat16(v);
            }
        }
    }

    if constexpr (ALPHA_H > 0) {
        const int head = (ALPHA_H == 4) ? blockIdx.x : 0;
        float avs[NREP], avd[NREP];
#pragma unroll
        for (int j = 0; j < NREP; ++j) {
            int cl = wn0 + j * 16 + fr;
            avs[j] = aSrcTab[head * BN + cl];
            avd[j] = aDstTab[head * BN + cl];
        }
        float pa[MREP][4] = {};
        float pd_[MREP][4] = {};
#pragma unroll
        for (int i = 0; i < MREP; ++i)
#pragma unroll
            for (int j = 0; j < NREP; ++j)
#pragma unroll
                for (int r = 0; r < 4; ++r) {
                    pa[i][r] += acc[i][j][r] * avs[j];
                    pd_[i][r] += acc[i][j][r] * avd[j];
                }
        // reduce over the 16 fr lanes
#pragma unroll
        for (int off = 1; off <= 8; off <<= 1)
#pragma unroll
            for (int i = 0; i < MREP; ++i)
#pragma unroll
                for (int r = 0; r < 4; ++r) {
                    pa[i][r] += __shfl_xor(pa[i][r], off);
                    pd_[i][r] += __shfl_xor(pd_[i][r], off);
                }
        // cross-wave (column-half) add via LDS
        float* lds_a = (float*)lds;        // BM floats
        float* lds_d = lds_a + BM;         // BM floats
        if ((wave & 1) == 0 && fr == 0) {
#pragma unroll
            for (int i = 0; i < MREP; ++i)
#pragma unroll
                for (int r = 0; r < 4; ++r) {
                    int rl = wm0 + i * 16 + fq * 4 + r;
                    lds_a[rl] = pa[i][r];
                    lds_d[rl] = pd_[i][r];
                }
        }
        __syncthreads();
        if ((wave & 1) == 1 && fr == 0) {
#pragma unroll
            for (int i = 0; i < MREP; ++i)
#pragma unroll
                for (int r = 0; r < 4; ++r) {
                    int rl = wm0 + i * 16 + fq * 4 + r;
                    int rowg = m0 + rl;
                    if (ALPHA_H == 4) {
                        asOut[rowg * 4 + head] = lds_a[rl] + pa[i][r];
                        adOut[rowg * 4 + head] = lds_d[rl] + pd_[i][r];
                    } else {
                        asOut[rowg] = lds_a[rl] + pa[i][r];
                        adOut[rowg] = lds_d[rl] + pd_[i][r];
                    }
                }
        }
    }
}

// ------------------------- gathers ------------------------------------------
// L1: gather X rows (128 ch bf16); one wave per dst; lane owns 2 channels,
// accumulates all 4 heads. Edge weights computed INLINE cooperatively:
// lanes 0-15 compute w[edge q][head h] (q=lane>>2, h=lane&3) from as4/ad4,
// broadcast via constant-index shfl. Pads masked via cnt.

__global__ void k_gatherX(const __hip_bfloat16* __restrict__ xb,
                          const float* __restrict__ as4, const float* __restrict__ ad4,
                          const int* __restrict__ cnt, const int* __restrict__ rp,
                          const int* __restrict__ col, unsigned* __restrict__ out32, int N) {
    int w = (blockIdx.x * blockDim.x + threadIdx.x) >> 6;
    int lane = threadIdx.x & 63;
    if (w >= N) return;
    int d = w;
    int r0 = rp[d], r1 = rp[d + 1];
    int r1r = r0 + cnt[d];
    const unsigned* xp = (const unsigned*)xb;
    int q = (lane >> 2) & 3, hh = lane & 3;
    float adv = ad4[d * 4 + hh];

    float acc[8] = {};
    float ws0 = 0.f, ws1 = 0.f, ws2 = 0.f, ws3 = 0.f;
    for (int e = r0; e < r1; e += 4) {
        int4 c4 = *(const int4*)&col[e];
        // cooperative weight computation (meaningful in lanes 0..15)
        int sq = (q == 0) ? c4.x : (q == 1) ? c4.y : (q == 2) ? c4.z : c4.w;
        float av = as4[sq * 4 + hh];
        float wv = (e + q < r1r) ? __expf(leaky(av + adv)) : 0.f;
        float w00 = __shfl(wv, 0),  w01 = __shfl(wv, 1),  w02 = __shfl(wv, 2),  w03 = __shfl(wv, 3);
        float w10 = __shfl(wv, 4),  w11 = __shfl(wv, 5),  w12 = __shfl(wv, 6),  w13 = __shfl(wv, 7);
        float w20 = __shfl(wv, 8),  w21 = __shfl(wv, 9),  w22 = __shfl(wv, 10), w23 = __shfl(wv, 11);
        float w30 = __shfl(wv, 12), w31 = __shfl(wv, 13), w32 = __shfl(wv, 14), w33 = __shfl(wv, 15);
        unsigned v0 = xp[(size_t)c4.x * 64 + lane];
        unsigned v1 = xp[(size_t)c4.y * 64 + lane];
        unsigned v2 = xp[(size_t)c4.z * 64 + lane];
        unsigned v3 = xp[(size_t)c4.w * 64 + lane];
        ws0 += (w00 + w10) + (w20 + w30);
        ws1 += (w01 + w11) + (w21 + w31);
        ws2 += (w02 + w12) + (w22 + w32);
        ws3 += (w03 + w13) + (w23 + w33);
        float f0, f1;
        f0 = bflo(v0); f1 = bfhi(v0);
        acc[0] += w00 * f0; acc[1] += w00 * f1;
        acc[2] += w01 * f0; acc[3] += w01 * f1;
        acc[4] += w02 * f0; acc[5] += w02 * f1;
        acc[6] += w03 * f0; acc[7] += w03 * f1;
        f0 = bflo(v1); f1 = bfhi(v1);
        acc[0] += w10 * f0; acc[1] += w10 * f1;
        acc[2] += w11 * f0; acc[3] += w11 * f1;
        acc[4] += w12 * f0; acc[5] += w12 * f1;
        acc[6] += w13 * f0; acc[7] += w13 * f1;
        f0 = bflo(v2); f1 = bfhi(v2);
        acc[0] += w20 * f0; acc[1] += w20 * f1;
        acc[2] += w21 * f0; acc[3] += w21 * f1;
        acc[4] += w22 * f0; acc[5] += w22 * f1;
        acc[6] += w23 * f0; acc[7] += w23 * f1;
        f0 = bflo(v3); f1 = bfhi(v3);
        acc[0] += w30 * f0; acc[1] += w30 * f1;
        acc[2] += w31 * f0; acc[3] += w31 * f1;
        acc[4] += w32 * f0; acc[5] += w32 * f1;
        acc[6] += w33 * f0; acc[7] += w33 * f1;
    }
    float i0 = 1.f / (ws0 + 1e-16f), i1 = 1.f / (ws1 + 1e-16f);
    float i2 = 1.f / (ws2 + 1e-16f), i3 = 1.f / (ws3 + 1e-16f);
    size_t ob = (size_t)d * 256 + lane;
    out32[ob]       = pack2(acc[0] * i0, acc[1] * i0);
    out32[ob + 64]  = pack2(acc[2] * i1, acc[3] * i1);
    out32[ob + 128] = pack2(acc[4] * i2, acc[5] * i2);
    out32[ob + 192] = pack2(acc[6] * i3, acc[7] * i3);
}

// L2: half-row gather of h2. blockIdx.z = column half (z slowest in dispatch
// order -> the two 25.5MB half working-sets are processed temporally apart,
// roughly doubling per-XCD L2 hit rate). One wave per node, uint2 (8B)/lane,
// 4 independent row loads per iter. Inline weights; pads masked via cnt.

template <bool DO_ELU>
__global__ void k_gather512(const __hip_bfloat16* __restrict__ hfeat,
                            const float* __restrict__ as4, const float* __restrict__ ad4,
                            const int* __restrict__ cnt, const int* __restrict__ rp,
                            const int* __restrict__ col, const float* __restrict__ bias,
                            __hip_bfloat16* __restrict__ out, int N) {
    int w = (blockIdx.x * blockDim.x + threadIdx.x) >> 6;
    int lane = threadIdx.x & 63;
    if (w >= N) return;
    int z = blockIdx.z;                   // column half
    int d = w;
    int r0 = rp[d], r1 = rp[d + 1];       // quad-aligned
    int r1r = r0 + cnt[d];                // real edge end
    int hd = z * 2 + (lane >> 5);         // head of my 4 channels
    float adv = ad4[d * 4 + hd];
    const uint2* hp = (const uint2*)hfeat;          // 128 uint2 per 512-ch row
    const unsigned coff = (unsigned)(z * 64 + lane);  // uint2 offset in row

    float acc[4] = {};
    float wsum = 0.f;
    for (int e = r0; e < r1; e += 4) {
        int4 c4 = *(const int4*)&col[e];
        float l0 = as4[c4.x * 4 + hd] + adv;
        float l1 = as4[c4.y * 4 + hd] + adv;
        float l2 = as4[c4.z * 4 + hd] + adv;
        float l3 = as4[c4.w * 4 + hd] + adv;
        uint2 v0 = hp[(size_t)c4.x * 128 + coff];
        uint2 v1 = hp[(size_t)c4.y * 128 + coff];
        uint2 v2 = hp[(size_t)c4.z * 128 + coff];
        uint2 v3 = hp[(size_t)c4.w * 128 + coff];
        float w0 = (e + 0 < r1r) ? __expf(leaky(l0)) : 0.f;
        float w1 = (e + 1 < r1r) ? __expf(leaky(l1)) : 0.f;
        float w2 = (e + 2 < r1r) ? __expf(leaky(l2)) : 0.f;
        float w3 = (e + 3 < r1r) ? __expf(leaky(l3)) : 0.f;
        wsum += (w0 + w1) + (w2 + w3);
        acc[0] += w0 * bflo(v0.x); acc[1] += w0 * bfhi(v0.x);
        acc[2] += w0 * bflo(v0.y); acc[3] += w0 * bfhi(v0.y);
        acc[0] += w1 * bflo(v1.x); acc[1] += w1 * bfhi(v1.x);
        acc[2] += w1 * bflo(v1.y); acc[3] += w1 * bfhi(v1.y);
        acc[0] += w2 * bflo(v2.x); acc[1] += w2 * bfhi(v2.x);
        acc[2] += w2 * bflo(v2.y); acc[3] += w2 * bfhi(v2.y);
        acc[0] += w3 * bflo(v3.x); acc[1] += w3 * bfhi(v3.x);
        acc[2] += w3 * bflo(v3.y); acc[3] += w3 * bfhi(v3.y);
    }

    float inv = 1.0f / (wsum + 1e-16f);
    int c = z * 256 + lane * 4;
    float o[4];
#pragma unroll
    for (int j = 0; j < 4; j++) {
        float v = acc[j] * inv + bias[c + j];
        if (DO_ELU) v = v > 0.f ? v : expm1f(v);
        o[j] = v;
    }
    *(uint2*)(out + (size_t)d * 512 + c) = make_uint2(pack2(o[0], o[1]), pack2(o[2], o[3]));
}

// L3: CT=64, H=1, f32 out: 16-lane groups each handle one edge, 4 edges/iter,
// inline weights (single head), pad masked via cnt.

__global__ void k_gather64(const __hip_bfloat16* __restrict__ hfeat,
                           const float* __restrict__ as1, const float* __restrict__ ad1,
                           const int* __restrict__ cnt, const int* __restrict__ rp,
                           const int* __restrict__ col, const float* __restrict__ bias,
                           float* __restrict__ out, int N) {
    int w = (blockIdx.x * blockDim.x + threadIdx.x) >> 6;
    int lane = threadIdx.x & 63;
    if (w >= N) return;
    int d = w;
    int r0 = rp[d], r1 = rp[d + 1];
    int r1r = r0 + cnt[d];
    float adv = ad1[d];
    int g = lane >> 4, cl = lane & 15;

    float a0 = 0.f, a1 = 0.f, a2 = 0.f, a3 = 0.f, wsum = 0.f;
    for (int e0 = r0; e0 < r1; e0 += 4) {
        int e = e0 + g;
        int s = col[e];
        float l = as1[s] + adv;
        uint2 q = *(const uint2*)(hfeat + (size_t)s * 64 + cl * 4);
        float wf = (e < r1r) ? __expf(leaky(l)) : 0.f;
        wsum += wf;
        a0 += wf * bflo(q.x);
        a1 += wf * bfhi(q.x);
        a2 += wf * bflo(q.y);
        a3 += wf * bfhi(q.y);
    }
#pragma unroll
    for (int off = 16; off <= 32; off <<= 1) {
        a0 += __shfl_xor(a0, off);
        a1 += __shfl_xor(a1, off);
        a2 += __shfl_xor(a2, off);
        a3 += __shfl_xor(a3, off);
        wsum += __shfl_xor(wsum, off);
    }
    if (g == 0) {
        float inv = 1.0f / (wsum + 1e-16f);
        float4 b4 = *(const float4*)&bias[cl * 4];
        float4 o = make_float4(a0 * inv + b4.x, a1 * inv + b4.y,
                               a2 * inv + b4.z, a3 * inv + b4.w);
        *(float4*)(out + (size_t)d * 64 + cl * 4) = o;
    }
}

// ------------------------- host launcher ------------------------------------

extern "C" void kernel_launch(void* const* d_in, const int* in_sizes, int n_in,
                              void* d_out, int out_size, void* d_ws, size_t ws_size,
                              hipStream_t stream) {
    const float* x   = (const float*)d_in[0];
    const int*   ei  = (const int*)d_in[1];
    const float* W1  = (const float*)d_in[2];
    const float* as1 = (const float*)d_in[3];
    const float* ad1 = (const float*)d_in[4];
    const float* b1  = (const float*)d_in[5];
    const float* W2  = (const float*)d_in[6];
    const float* as2 = (const float*)d_in[7];
    const float* ad2 = (const float*)d_in[8];
    const float* b2  = (const float*)d_in[9];
    const float* W3  = (const float*)d_in[10];
    const float* as3 = (const float*)d_in[11];
    const float* ad3 = (const float*)d_in[12];
    const float* b3  = (const float*)d_in[13];

    const int N = in_sizes[0] / 128;     // 50000
    const int E = in_sizes[1] / 2;       // 400000
    const int Etot = E + N;
    const int EP = (Etot + 3 * N + 255) & ~255;  // padded-edge upper bound
    const int Mp = (N + 127) & ~127;     // 50048

    char* ws = (char*)d_ws;
    size_t off = 0;
    auto alloc = [&](size_t bytes) -> void* {
        void* p = ws + off;
        off = (off + bytes + 255) & ~(size_t)255;
        return p;
    };
    __hip_bfloat16* hbuf = (__hip_bfloat16*)alloc((size_t)Mp * 512 * 2);  // h2 / h3
    __hip_bfloat16* fbuf = (__hip_bfloat16*)alloc((size_t)Mp * 512 * 2);  // f1 / f2
    __hip_bfloat16* xagg = (__hip_bfloat16*)alloc((size_t)Mp * 512 * 2);  // L1 gathered X
    __hip_bfloat16* xb   = (__hip_bfloat16*)alloc((size_t)Mp * 128 * 2);
    __hip_bfloat16* Wt1  = (__hip_bfloat16*)alloc((size_t)512 * 128 * 2);
    __hip_bfloat16* Wt2  = (__hip_bfloat16*)alloc((size_t)512 * 512 * 2);
    __hip_bfloat16* Wt3  = (__hip_bfloat16*)alloc((size_t)64 * 512 * 2);
    float* aS   = (float*)alloc((size_t)Mp * 4 * 4);
    float* aD   = (float*)alloc((size_t)Mp * 4 * 4);
    float* aS3  = (float*)alloc((size_t)Mp * 4);
    float* aD3  = (float*)alloc((size_t)Mp * 4);
    float* va8  = (float*)alloc(128 * 8 * 4);
    int* cnt  = (int*)alloc((size_t)N * 4);
    int* rp   = (int*)alloc((size_t)(N + 1) * 4);
    int* cur  = (int*)alloc((size_t)N * 4);
    int* col  = (int*)alloc((size_t)EP * 4);
    int* blks = (int*)alloc(64 * 4);

    // ---- CSR build (padded) ----
    hipMemsetAsync(cnt, 0, (size_t)N * 4, stream);
    int thr = 256;
    k_count<<<(Etot + thr - 1) / thr, thr, 0, stream>>>(ei, E, N, cnt);
    int nblk = (N + 1023) / 1024;
    k_scan1<<<nblk, 256, 0, stream>>>(cnt, N, rp, blks);
    k_scan3<<<(N + 255) / 256, 256, 0, stream>>>(rp, blks, cnt, N, nblk, cur, col);
    k_fill<<<(Etot + thr - 1) / thr, thr, 0, stream>>>(ei, E, N, cur, col);

    // ---- one-time casts + va + fused alpha1 ----
    {
        dim3 g1(128 / 32, 512 / 32);
        k_castT<<<g1, 256, 0, stream>>>(W1, Wt1, 128, 512);
        dim3 g2(512 / 32, 512 / 32);
        k_castT<<<g2, 256, 0, stream>>>(W2, Wt2, 512, 512);
        dim3 g3(512 / 32, 64 / 32);
        k_castT<<<g3, 256, 0, stream>>>(W3, Wt3, 512, 64);
        k_va1<<<1, 512, 0, stream>>>(W1, as1, ad1, va8);
        k_cast_alpha<<<(Mp + 3) / 4, 256, 0, stream>>>(x, xb, va8, aS, aD, N, Mp);
    }

    int gatBlocks = (N + 3) / 4;

    // ---- Layer 1: gather X (inline weights), fused per-head GEMM ----
    k_gatherX<<<gatBlocks, 256, 0, stream>>>(xb, aS, aD, cnt, rp, col,
                                             (unsigned*)xagg, N);
    {
        dim3 g(1, Mp / 128, 4);  // z = head
        k_gemm_mfma<128, 128, true, 0><<<g, 256, 0, stream>>>(
            xagg, Wt1, fbuf, 512, 512, 128, 128, 128 * 128, 128, b1,
            nullptr, nullptr, nullptr, nullptr);
    }

    // ---- Layer 2: GEMM w/ fused alpha2, half-sliced gather (+b2, ELU) ----
    {
        dim3 g(4, Mp / 128, 1);  // x = head (BN=128 per head)
        k_gemm_mfma<128, 128, false, 4><<<g, 256, 0, stream>>>(
            fbuf, Wt2, hbuf, 512, 512, 512, 0, 0, 0, nullptr,
            as2, ad2, aS, aD);
    }
    {
        dim3 g(gatBlocks, 1, 2);  // z = column half (temporal separation)
        k_gather512<true><<<g, 256, 0, stream>>>(hbuf, aS, aD, cnt, rp, col, b2,
                                                 fbuf, N);
    }

    // ---- Layer 3: GEMM (BM=64) w/ fused alpha3, gather 64ch (+b3) ----
    {
        dim3 g(1, Mp / 64, 1);
        k_gemm_mfma<64, 64, false, 1><<<g, 256, 0, stream>>>(
            fbuf, Wt3, hbuf, 512, 64, 512, 0, 0, 0, nullptr,
            as3, ad3, aS3, aD3);
    }
    k_gather64<<<gatBlocks, 256, 0, stream>>>(hbuf, aS3, aD3, cnt, rp, col, b3,
                                              (float*)d_out, N);
}